// Round 8
// baseline (485.574 us; speedup 1.0000x reference)
//
#include <hip/hip_runtime.h>
#include <math.h>

#define B_ 16
#define NAV_ 36
#define H_ 120
#define W_ 160
#define HID_ 512
#define PLANES (B_*NAV_)          // 576
#define PLANE_PX (H_*W_)          // 19200
#define CANVAS_H 360
#define CANVAS_W 1920
#define CANVAS_PX (CANVAS_H*CANVAS_W)  // 691200

// workspace offsets (in floats)
#define WS_NAV    0                                   // 576
#define WS_FATT   576                                 // 64
#define WS_KERN   640                                 // 28800
#define WS_TD     29440
#define WS_CANVAS (WS_TD + PLANES*PLANE_PX)
#define WS_POOL1  (WS_CANVAS + B_*CANVAS_PX)
#define WS_VF     (WS_POOL1 + B_*2*19*89)

__device__ __forceinline__ float sigmoidf_(float x) { return 1.f / (1.f + expf(-x)); }

// 4-px-wide 5-tap MAC with NAMED weight scalars (nothing indexable -> regs).
#define ROW_MACN(ACC, W0,W1,W2,W3,W4, A, Bv, C)                               \
    ACC.x += W0*A.z  + W1*A.w  + W2*Bv.x + W3*Bv.y + W4*Bv.z;                 \
    ACC.y += W0*A.w  + W1*Bv.x + W2*Bv.y + W3*Bv.z + W4*Bv.w;                 \
    ACC.z += W0*Bv.x + W1*Bv.y + W2*Bv.z + W3*Bv.w + W4*C.x;                  \
    ACC.w += W0*Bv.y + W1*Bv.z + W2*Bv.w + W3*C.x  + W4*C.y;

// ---------------------------------------------------------------------------
// Kernel 0: tiny precompute.  grid 16, 256 threads.
// ---------------------------------------------------------------------------
__global__ __launch_bounds__(256)
void k_pre(const float* __restrict__ wctx, const float* __restrict__ dw1,
           const float* __restrict__ db1, const float* __restrict__ dw2,
           const float* __restrict__ db2, const float* __restrict__ dynf,
           const float* __restrict__ numnav, float* __restrict__ ws)
{
    const int tid = threadIdx.x;
    const int b = blockIdx.x;
    __shared__ float sh[128];
    __shared__ float sred[8];
    __shared__ float nv[36];
    __shared__ float nms[2];
    if (tid < 128) {
        float acc = db1[tid];
        for (int k = 0; k < HID_; ++k) acc += wctx[b*HID_ + k] * dw1[k*128 + tid];
        sh[tid] = fmaxf(acc, 0.f);
    }
    __syncthreads();
    if (tid < 4) {
        float acc = db2[tid];
        for (int j = 0; j < 128; ++j) acc += sh[j] * dw2[j*4 + tid];
        sred[tid] = acc;
    }
    __syncthreads();
    if (tid == 0) {
        float m = fmaxf(fmaxf(sred[0], sred[1]), fmaxf(sred[2], sred[3]));
        float e0 = expf(sred[0]-m), e1 = expf(sred[1]-m), e2 = expf(sred[2]-m), e3 = expf(sred[3]-m);
        float s = e0+e1+e2+e3;
        sred[4] = e0/s; sred[5] = e1/s; sred[6] = e2/s; sred[7] = e3/s;
        ws[WS_FATT + b*4+0] = sred[4]; ws[WS_FATT + b*4+1] = sred[5];
        ws[WS_FATT + b*4+2] = sred[6]; ws[WS_FATT + b*4+3] = sred[7];
    }
    __syncthreads();
    {
        const float fa0 = sred[4], fa1 = sred[5], fa2 = sred[6], fa3 = sred[7];
        for (int e = tid; e < 1800; e += 256) {
            float v = fa0*dynf[e] + fa1*dynf[1800+e] + fa2*dynf[3600+e] + fa3*dynf[5400+e];
            ws[WS_KERN + b*1800 + e] = v;
        }
    }
    if (tid < 36) nv[tid] = numnav[b*NAV_ + tid];
    __syncthreads();
    if (tid == 0) {
        float m = nv[0];
        for (int i = 1; i < 36; ++i) m = fmaxf(m, nv[i]);
        float s = 0.f;
        for (int i = 0; i < 36; ++i) s += expf(nv[i]-m);
        nms[0] = m; nms[1] = s;
    }
    __syncthreads();
    if (tid < 36) ws[WS_NAV + b*NAV_ + tid] = expf(nv[tid]-nms[0]) / nms[1];
}

// ---------------------------------------------------------------------------
// Kernel 1: grouped conv1 -> total_depth (ws).  grid (5, 576), 256 thr.
// Each block: 960 4-px tasks (3.75/thread).  ky loop NOT unrolled so only
// 10 weights live at a time (LDS broadcast) -> low VGPR, high occupancy.
// ---------------------------------------------------------------------------
__global__ __launch_bounds__(256)
void k_td(const float* __restrict__ d0, const float* __restrict__ d1,
          const float* __restrict__ conv1_w, const float* __restrict__ conv1_b,
          float* __restrict__ ws)
{
    const int tid = threadIdx.x;
    const int plane = blockIdx.y;
    const int g = plane % NAV_;
    __shared__ float swt[50];
    __shared__ float sb[1];
    if (tid < 50) swt[tid] = conv1_w[g*50 + tid];
    if (tid == 50) sb[0] = conv1_b[g];
    __syncthreads();
    const float bias = sb[0];
    const float* p0 = d0 + (size_t)plane*PLANE_PX;
    const float* p1 = d1 + (size_t)plane*PLANE_PX;
    float* outp = ws + WS_TD + (size_t)plane*PLANE_PX;
    const float4 z4 = make_float4(0.f, 0.f, 0.f, 0.f);

    const int t_end = blockIdx.x*960 + 960;
    for (int task = blockIdx.x*960 + tid; task < t_end; task += 256) {
        const int y = task / 40;
        const int c4 = task % 40;
        const int x0 = c4*4;
        const bool hasL = c4 > 0, hasR = c4 < 39;
        float4 acc = make_float4(bias, bias, bias, bias);
        #pragma unroll 1
        for (int ky = 0; ky < 5; ++ky) {
            const int yy = y + ky - 2;
            const bool vy = (unsigned)yy < (unsigned)H_;
            const float* r0 = p0 + (vy ? yy : 0)*W_ + x0;
            const float* r1 = p1 + (vy ? yy : 0)*W_ + x0;
            float4 A0 = (vy && hasL) ? *(const float4*)(r0-4) : z4;
            float4 B0 =  vy          ? *(const float4*)(r0)   : z4;
            float4 C0 = (vy && hasR) ? *(const float4*)(r0+4) : z4;
            float4 A1 = (vy && hasL) ? *(const float4*)(r1-4) : z4;
            float4 B1 =  vy          ? *(const float4*)(r1)   : z4;
            float4 C1 = (vy && hasR) ? *(const float4*)(r1+4) : z4;
            const int k5 = ky*5;
            float u0 = swt[k5], u1 = swt[k5+1], u2 = swt[k5+2], u3 = swt[k5+3], u4 = swt[k5+4];
            ROW_MACN(acc, u0, u1, u2, u3, u4, A0, B0, C0)
            float q0 = swt[25+k5], q1 = swt[26+k5], q2 = swt[27+k5], q3 = swt[28+k5], q4 = swt[29+k5];
            ROW_MACN(acc, q0, q1, q2, q3, q4, A1, B1, C1)
        }
        *(float4*)(outp + y*W_ + x0) = acc;
    }
}

// ---------------------------------------------------------------------------
// Kernel 2: dynamic grouped conv (td, obj) -> canvas.  grid (5, 576).
// Same structure as k_td.
// ---------------------------------------------------------------------------
__global__ __launch_bounds__(256)
void k_dyn(const float* __restrict__ obj, float* __restrict__ ws)
{
    const int tid = threadIdx.x;
    const int plane = blockIdx.y;
    const int b = plane / NAV_;
    const int g = plane % NAV_;
    __shared__ float swk[50];
    __shared__ float sa[1];
    if (tid < 50) swk[tid] = ws[WS_KERN + plane*50 + tid];
    if (tid == 50) sa[0] = ws[WS_NAV + plane];
    __syncthreads();
    const float a = sa[0];
    const float* pt = ws + WS_TD + (size_t)plane*PLANE_PX;
    const float* po = obj + (size_t)plane*PLANE_PX;
    const int rowblk = 2 - g/12;
    const int colblk = g % 12;
    float* cbase = ws + WS_CANVAS + (size_t)b*CANVAS_PX + (size_t)rowblk*H_*CANVAS_W + colblk*W_;
    const float4 z4 = make_float4(0.f, 0.f, 0.f, 0.f);

    const int t_end = blockIdx.x*960 + 960;
    for (int task = blockIdx.x*960 + tid; task < t_end; task += 256) {
        const int y = task / 40;
        const int c4 = task % 40;
        const int x0 = c4*4;
        const bool hasL = c4 > 0, hasR = c4 < 39;
        float4 acc = z4;
        #pragma unroll 1
        for (int ky = 0; ky < 5; ++ky) {
            const int yy = y + ky - 2;
            const bool vy = (unsigned)yy < (unsigned)H_;
            const float* r0 = pt + (vy ? yy : 0)*W_ + x0;
            const float* r1 = po + (vy ? yy : 0)*W_ + x0;
            float4 A0 = (vy && hasL) ? *(const float4*)(r0-4) : z4;
            float4 B0 =  vy          ? *(const float4*)(r0)   : z4;
            float4 C0 = (vy && hasR) ? *(const float4*)(r0+4) : z4;
            float4 A1 = (vy && hasL) ? *(const float4*)(r1-4) : z4;
            float4 B1 =  vy          ? *(const float4*)(r1)   : z4;
            float4 C1 = (vy && hasR) ? *(const float4*)(r1+4) : z4;
            const int k5 = ky*5;
            float u0 = swk[k5], u1 = swk[k5+1], u2 = swk[k5+2], u3 = swk[k5+3], u4 = swk[k5+4];
            ROW_MACN(acc, u0, u1, u2, u3, u4, A0, B0, C0)
            float q0 = swk[25+k5], q1 = swk[26+k5], q2 = swk[27+k5], q3 = swk[28+k5], q4 = swk[29+k5];
            ROW_MACN(acc, q0, q1, q2, q3, q4, A1, B1, C1)
        }
        *(float4*)(cbase + (size_t)y*CANVAS_W + x0) =
            make_float4(a*acc.x, a*acc.y, a*acc.z, a*acc.w);
    }
}

// ---------------------------------------------------------------------------
// Kernel 3: conv2_1 (k5, stride (5,7), dil 10) + avgpool3x3/3 -> pool1 (ws).
// grid 608, 256 threads.
// ---------------------------------------------------------------------------
__global__ __launch_bounds__(256)
void k_conv2a(const float* __restrict__ w21p, const float* __restrict__ b21p,
              float* __restrict__ ws)
{
    const int blk = blockIdx.x;          // (b*2+ver)*19 + a
    const int a = blk % 19;
    const int bv = blk / 19;
    const int ver = bv & 1;
    const int b = bv >> 1;
    const int coloff = ver ? (CANVAS_W - W_) : 0;   // 1760

    __shared__ float s1[3*267];
    __shared__ float swt[25];
    if (threadIdx.x < 25) swt[threadIdx.x] = w21p[threadIdx.x];
    __syncthreads();
    const float b21 = b21p[0];
    const float* cv = ws + WS_CANVAS + (size_t)b*CANVAS_PX;

    for (int px = threadIdx.x; px < 3*267; px += 256) {
        const int row = px / 267;
        const int v = px % 267;
        const int u = 3*a + row;
        float acc = b21;
        #pragma unroll
        for (int ky = 0; ky < 5; ++ky) {
            const float* rp = cv + (5*u + 10*ky)*CANVAS_W;
            #pragma unroll
            for (int kx = 0; kx < 5; ++kx) {
                int c = 7*v + 10*kx + coloff;
                if (c >= CANVAS_W) c -= CANVAS_W;
                acc += swt[ky*5+kx] * rp[c];
            }
        }
        s1[px] = acc;
    }
    __syncthreads();
    if (threadIdx.x < 89) {
        const int bb = threadIdx.x;
        float s = 0.f;
        #pragma unroll
        for (int i = 0; i < 3; ++i)
            #pragma unroll
            for (int j = 0; j < 3; ++j)
                s += s1[i*267 + 3*bb + j];
        ws[WS_POOL1 + blk*89 + bb] = s * (1.f/9.f);
    }
}

// ---------------------------------------------------------------------------
// Kernel 4: conv2_2 + avgpool(3,9)/3 + v2 roll + combine + flip + softmax/10
// + mask.  grid 16, 256 threads.
// ---------------------------------------------------------------------------
__global__ __launch_bounds__(256)
void k_conv2b(const float* __restrict__ w22p, const float* __restrict__ b22p,
              const int* __restrict__ navidx, float* __restrict__ ws,
              float* __restrict__ out)
{
    const int b = blockIdx.x;
    __shared__ float p[2*19*89];
    __shared__ float s2[2*9*43];
    __shared__ float svf[36];
    __shared__ float sms[2];
    __shared__ float swt[9];

    for (int i = threadIdx.x; i < 2*19*89; i += 256)
        p[i] = ws[WS_POOL1 + (b*2)*19*89 + i];
    if (threadIdx.x < 9) swt[threadIdx.x] = w22p[threadIdx.x];
    const float b22 = b22p[0];
    __syncthreads();

    for (int t = threadIdx.x; t < 2*9*43; t += 256) {
        const int ver = t / 387;
        const int r = t % 387;
        const int pp = r / 43;
        const int q = r % 43;
        float acc = b22;
        #pragma unroll
        for (int i = 0; i < 3; ++i)
            #pragma unroll
            for (int j = 0; j < 3; ++j)
                acc += swt[i*3+j] * p[(ver*19 + (2*pp+i))*89 + 2*q + 2*j];
        s2[ver*387 + pp*43 + q] = acc;
    }
    __syncthreads();

    if (threadIdx.x < 36) {
        const int gg = threadIdx.x;
        const int io = 2 - gg/12;
        const int j  = gg % 12;
        const int j2 = (j + 1) % 12;
        float s = 0.f;
        #pragma unroll
        for (int ii = 0; ii < 3; ++ii)
            #pragma unroll
            for (int jj = 0; jj < 9; ++jj)
                s += s2[(3*io+ii)*43 + 3*j + jj] + s2[387 + (3*io+ii)*43 + 3*j2 + jj];
        svf[gg] = s * (0.5f/27.f);
    }
    __syncthreads();
    if (threadIdx.x == 0) {
        float m = svf[0];
        for (int i = 1; i < 36; ++i) m = fmaxf(m, svf[i]);
        float s = 0.f;
        for (int i = 0; i < 36; ++i) s += expf((svf[i]-m)*0.1f);
        sms[0] = m; sms[1] = s;
    }
    __syncthreads();
    if (threadIdx.x < 36) {
        const float v = expf((svf[threadIdx.x]-sms[0])*0.1f) / sms[1];
        ws[WS_VF + b*36 + threadIdx.x] = v;
        out[16384 + b*36 + threadIdx.x] = v;
    }
    if (threadIdx.x < 37) {
        const int j = threadIdx.x;
        float v = (j == 0) ? 1.f : 0.f;
        #pragma unroll
        for (int t = 0; t < 8; ++t)
            if (navidx[b*8+t] + 1 == j) v = 1.f;
        out[16960 + b*37 + j] = v;
    }
}

// ---------------------------------------------------------------------------
// Kernel 5: LSTM GEMM + pointwise.  grid 256, 256 threads.
// ---------------------------------------------------------------------------
#define CT_STRIDE 20
__global__ __launch_bounds__(256)
void k_lstm(const float* __restrict__ wctx, const float* __restrict__ pre_action,
            const float* __restrict__ h0, const float* __restrict__ c0,
            const float* __restrict__ w_ih, const float* __restrict__ w_hh,
            const float* __restrict__ b_ih, const float* __restrict__ b_hh,
            const float* __restrict__ ws, float* __restrict__ out)
{
    __shared__ float cT[1096*CT_STRIDE];
    __shared__ float red[8*32*16];
    __shared__ float gatev[8][16];
    const int tid = threadIdx.x;

    for (int idx = tid; idx < 1096*16; idx += 256) {
        const int k = idx >> 4;
        const int bb = idx & 15;
        float v;
        if (k < 512)       v = wctx[bb*512 + k];
        else if (k < 548)  v = ws[WS_VF + bb*36 + (k-512)];
        else if (k < 552)  v = ws[WS_FATT + bb*4 + (k-548)];
        else if (k < 584)  v = pre_action[bb*32 + (k-552)];
        else               v = h0[bb*512 + (k-584)];
        cT[k*CT_STRIDE + bb] = v;
    }
    __syncthreads();

    const int rl = tid >> 5;
    const int lane = tid & 31;
    const int u0 = blockIdx.x*2;
    const int ul = rl & 1;
    const int gate = rl >> 1;
    const int r = u0 + ul + gate*512;

    float acc[16];
    #pragma unroll
    for (int i = 0; i < 16; ++i) acc[i] = 0.f;

    const float* wih_r = w_ih + (size_t)r*584;
    for (int k = lane; k < 584; k += 32) {
        const float wv = wih_r[k];
        const float* cp = cT + k*CT_STRIDE;
        #pragma unroll
        for (int i = 0; i < 16; ++i) acc[i] += wv*cp[i];
    }
    const float* whh_r = w_hh + (size_t)r*512;
    for (int k = lane; k < 512; k += 32) {
        const float wv = whh_r[k];
        const float* cp = cT + (584+k)*CT_STRIDE;
        #pragma unroll
        for (int i = 0; i < 16; ++i) acc[i] += wv*cp[i];
    }
    float* rp = red + (rl*32 + lane)*16;
    #pragma unroll
    for (int i = 0; i < 16; ++i) rp[i] = acc[i];
    __syncthreads();

    if (tid < 128) {
        const int rr = tid >> 4;
        const int bb = tid & 15;
        const int rrow = u0 + (rr & 1) + (rr >> 1)*512;
        float s = b_ih[rrow] + b_hh[rrow];
        for (int l = 0; l < 32; ++l) s += red[(rr*32 + l)*16 + bb];
        gatev[rr][bb] = s;
    }
    __syncthreads();

    if (tid < 32) {
        const int ul2 = tid >> 4;
        const int bb = tid & 15;
        const int u = u0 + ul2;
        const float gi = gatev[0+ul2][bb];
        const float gf = gatev[2+ul2][bb];
        const float gg = gatev[4+ul2][bb];
        const float go = gatev[6+ul2][bb];
        const float c1 = sigmoidf_(gf)*c0[bb*512+u] + sigmoidf_(gi)*tanhf(gg);
        const float h1 = sigmoidf_(go)*tanhf(c1);
        out[bb*512 + u] = h1;
        out[8192 + bb*512 + u] = c1;
    }
}

// ---------------------------------------------------------------------------
extern "C" void kernel_launch(void* const* d_in, const int* in_sizes, int n_in,
                              void* d_out, int out_size, void* d_ws, size_t ws_size,
                              hipStream_t stream)
{
    const float* d0        = (const float*)d_in[0];
    const float* d1        = (const float*)d_in[1];
    const float* obj       = (const float*)d_in[2];
    const float* numnav    = (const float*)d_in[3];
    const float* preact    = (const float*)d_in[4];
    const float* h0        = (const float*)d_in[5];
    const float* c0        = (const float*)d_in[6];
    const float* wctx      = (const float*)d_in[7];
    const int*   navidx    = (const int*)d_in[8];
    const float* conv1_w   = (const float*)d_in[9];
    const float* conv1_b   = (const float*)d_in[10];
    const float* dynf      = (const float*)d_in[11];
    const float* dw1       = (const float*)d_in[12];
    const float* db1       = (const float*)d_in[13];
    const float* dw2       = (const float*)d_in[14];
    const float* db2       = (const float*)d_in[15];
    const float* w21       = (const float*)d_in[16];
    const float* b21       = (const float*)d_in[17];
    const float* w22       = (const float*)d_in[18];
    const float* b22       = (const float*)d_in[19];
    const float* wih       = (const float*)d_in[20];
    const float* whh       = (const float*)d_in[21];
    const float* bih       = (const float*)d_in[22];
    const float* bhh       = (const float*)d_in[23];
    float* ws  = (float*)d_ws;
    float* out = (float*)d_out;

    dim3 blk(256);
    k_pre   <<<dim3(16),      blk, 0, stream>>>(wctx, dw1, db1, dw2, db2, dynf, numnav, ws);
    k_td    <<<dim3(5, 576),  blk, 0, stream>>>(d0, d1, conv1_w, conv1_b, ws);
    k_dyn   <<<dim3(5, 576),  blk, 0, stream>>>(obj, ws);
    k_conv2a<<<dim3(608),     blk, 0, stream>>>(w21, b21, ws);
    k_conv2b<<<dim3(16),      blk, 0, stream>>>(w22, b22, navidx, ws, out);
    k_lstm  <<<dim3(256),     blk, 0, stream>>>(wctx, preact, h0, c0, wih, whh,
                                                bih, bhh, ws, out);
}

// Round 9
// 216.570 us; speedup vs baseline: 2.2421x; 2.2421x over previous
//
#include <hip/hip_runtime.h>
#include <math.h>

#define B_ 16
#define NAV_ 36
#define H_ 120
#define W_ 160
#define HID_ 512
#define PLANES (B_*NAV_)          // 576
#define PLANE_PX (H_*W_)          // 19200
#define CANVAS_H 360
#define CANVAS_W 1920
#define CANVAS_PX (CANVAS_H*CANVAS_W)  // 691200

// LDS-staged conv tiling: band of 12 output rows, 16 staged rows,
// padded row of 172 floats (4 left zero-pad, 160 image, 8 right zero-pad).
#define OUT_H 12
#define ST_ROWS 16                // OUT_H + 4
#define LSTR 172

// workspace offsets (in floats)
#define WS_NAV    0                                   // 576
#define WS_FATT   576                                 // 64
#define WS_KERN   640                                 // 28800
#define WS_TD     29440
#define WS_CANVAS (WS_TD + PLANES*PLANE_PX)
#define WS_POOL1  (WS_CANVAS + B_*CANVAS_PX)
#define WS_VF     (WS_POOL1 + B_*2*19*89)

__device__ __forceinline__ float sigmoidf_(float x) { return 1.f / (1.f + expf(-x)); }

// 4-px-wide 5-tap MAC with NAMED weight scalars.
#define ROW_MACN(ACC, W0,W1,W2,W3,W4, A, Bv, C)                               \
    ACC.x += W0*A.z  + W1*A.w  + W2*Bv.x + W3*Bv.y + W4*Bv.z;                 \
    ACC.y += W0*A.w  + W1*Bv.x + W2*Bv.y + W3*Bv.z + W4*Bv.w;                 \
    ACC.z += W0*Bv.x + W1*Bv.y + W2*Bv.z + W3*Bv.w + W4*C.x;                  \
    ACC.w += W0*Bv.y + W1*Bv.z + W2*Bv.w + W3*C.x  + W4*C.y;

// ---------------------------------------------------------------------------
// Kernel 0: tiny precompute.  grid 16, 256 threads.
// ---------------------------------------------------------------------------
__global__ __launch_bounds__(256)
void k_pre(const float* __restrict__ wctx, const float* __restrict__ dw1,
           const float* __restrict__ db1, const float* __restrict__ dw2,
           const float* __restrict__ db2, const float* __restrict__ dynf,
           const float* __restrict__ numnav, float* __restrict__ ws)
{
    const int tid = threadIdx.x;
    const int b = blockIdx.x;
    __shared__ float sh[128];
    __shared__ float sred[8];
    __shared__ float nv[36];
    __shared__ float nms[2];
    if (tid < 128) {
        float acc = db1[tid];
        for (int k = 0; k < HID_; ++k) acc += wctx[b*HID_ + k] * dw1[k*128 + tid];
        sh[tid] = fmaxf(acc, 0.f);
    }
    __syncthreads();
    if (tid < 4) {
        float acc = db2[tid];
        for (int j = 0; j < 128; ++j) acc += sh[j] * dw2[j*4 + tid];
        sred[tid] = acc;
    }
    __syncthreads();
    if (tid == 0) {
        float m = fmaxf(fmaxf(sred[0], sred[1]), fmaxf(sred[2], sred[3]));
        float e0 = expf(sred[0]-m), e1 = expf(sred[1]-m), e2 = expf(sred[2]-m), e3 = expf(sred[3]-m);
        float s = e0+e1+e2+e3;
        sred[4] = e0/s; sred[5] = e1/s; sred[6] = e2/s; sred[7] = e3/s;
        ws[WS_FATT + b*4+0] = sred[4]; ws[WS_FATT + b*4+1] = sred[5];
        ws[WS_FATT + b*4+2] = sred[6]; ws[WS_FATT + b*4+3] = sred[7];
    }
    __syncthreads();
    {
        const float fa0 = sred[4], fa1 = sred[5], fa2 = sred[6], fa3 = sred[7];
        for (int e = tid; e < 1800; e += 256) {
            float v = fa0*dynf[e] + fa1*dynf[1800+e] + fa2*dynf[3600+e] + fa3*dynf[5400+e];
            ws[WS_KERN + b*1800 + e] = v;
        }
    }
    if (tid < 36) nv[tid] = numnav[b*NAV_ + tid];
    __syncthreads();
    if (tid == 0) {
        float m = nv[0];
        for (int i = 1; i < 36; ++i) m = fmaxf(m, nv[i]);
        float s = 0.f;
        for (int i = 0; i < 36; ++i) s += expf(nv[i]-m);
        nms[0] = m; nms[1] = s;
    }
    __syncthreads();
    if (tid < 36) ws[WS_NAV + b*NAV_ + tid] = expf(nv[tid]-nms[0]) / nms[1];
}

// ---------------------------------------------------------------------------
// Kernel 1: grouped conv1 -> total_depth (ws).  grid (10, 576), 256 thr.
// Stage band into zero-padded LDS (each byte once); compute windows from
// LDS (separate pipe -> off the L1/vmem-issue path that bound R8).
// ---------------------------------------------------------------------------
__global__ __launch_bounds__(256)
void k_td(const float* __restrict__ d0, const float* __restrict__ d1,
          const float* __restrict__ conv1_w, const float* __restrict__ conv1_b,
          float* __restrict__ ws)
{
    const int tid = threadIdx.x;
    const int band = blockIdx.x;      // 0..9
    const int plane = blockIdx.y;
    const int g = plane % NAV_;
    const int r0 = band * OUT_H;

    __shared__ __align__(16) float inL[2*ST_ROWS*LSTR];   // 22016 B
    __shared__ float swt[50];
    __shared__ float sb[1];
    if (tid < 50) swt[tid] = conv1_w[g*50 + tid];
    if (tid == 50) sb[0] = conv1_b[g];

    const float4 z4 = make_float4(0.f, 0.f, 0.f, 0.f);
    // stage: 2 ch x 16 rows x 43 float4s
    for (int i = tid; i < 2*ST_ROWS*43; i += 256) {
        const int ch  = i / (ST_ROWS*43);
        const int rem = i % (ST_ROWS*43);
        const int row = rem / 43;
        const int c4  = rem % 43;
        const int gr  = r0 - 2 + row;
        float4 v = z4;
        if (c4 >= 1 && c4 <= 40 && (unsigned)gr < (unsigned)H_)
            v = *(const float4*)((ch ? d1 : d0) + (size_t)plane*PLANE_PX + gr*W_ + (c4*4 - 4));
        *(float4*)&inL[(ch*ST_ROWS + row)*LSTR + c4*4] = v;
    }
    __syncthreads();

    const float bias = sb[0];
    float* outp = ws + WS_TD + (size_t)plane*PLANE_PX + r0*W_;
    for (int t = tid; t < OUT_H*40; t += 256) {
        const int yr = t / 40;
        const int s  = t % 40;
        const int x0 = s*4;
        float4 acc = make_float4(bias, bias, bias, bias);
        #pragma unroll 1
        for (int ky = 0; ky < 5; ++ky) {
            const float* p0 = &inL[(yr + ky)*LSTR + x0];
            const float* p1 = &inL[(ST_ROWS + yr + ky)*LSTR + x0];
            float4 A0 = *(const float4*)(p0);
            float4 B0 = *(const float4*)(p0 + 4);
            float4 C0 = *(const float4*)(p0 + 8);
            float4 A1 = *(const float4*)(p1);
            float4 B1 = *(const float4*)(p1 + 4);
            float4 C1 = *(const float4*)(p1 + 8);
            const int k5 = ky*5;
            float u0 = swt[k5], u1 = swt[k5+1], u2 = swt[k5+2], u3 = swt[k5+3], u4 = swt[k5+4];
            ROW_MACN(acc, u0, u1, u2, u3, u4, A0, B0, C0)
            float q0 = swt[25+k5], q1 = swt[26+k5], q2 = swt[27+k5], q3 = swt[28+k5], q4 = swt[29+k5];
            ROW_MACN(acc, q0, q1, q2, q3, q4, A1, B1, C1)
        }
        *(float4*)(outp + yr*W_ + x0) = acc;
    }
}

// ---------------------------------------------------------------------------
// Kernel 2: dynamic grouped conv (td, obj) -> canvas.  grid (10, 576).
// Same LDS-staged structure.
// ---------------------------------------------------------------------------
__global__ __launch_bounds__(256)
void k_dyn(const float* __restrict__ obj, float* __restrict__ ws)
{
    const int tid = threadIdx.x;
    const int band = blockIdx.x;
    const int plane = blockIdx.y;
    const int b = plane / NAV_;
    const int g = plane % NAV_;
    const int r0 = band * OUT_H;

    __shared__ __align__(16) float inL[2*ST_ROWS*LSTR];
    __shared__ float swk[50];
    __shared__ float sa[1];
    if (tid < 50) swk[tid] = ws[WS_KERN + plane*50 + tid];
    if (tid == 50) sa[0] = ws[WS_NAV + plane];

    const float* td = ws + WS_TD + (size_t)plane*PLANE_PX;
    const float* po = obj + (size_t)plane*PLANE_PX;
    const float4 z4 = make_float4(0.f, 0.f, 0.f, 0.f);
    for (int i = tid; i < 2*ST_ROWS*43; i += 256) {
        const int ch  = i / (ST_ROWS*43);
        const int rem = i % (ST_ROWS*43);
        const int row = rem / 43;
        const int c4  = rem % 43;
        const int gr  = r0 - 2 + row;
        float4 v = z4;
        if (c4 >= 1 && c4 <= 40 && (unsigned)gr < (unsigned)H_)
            v = *(const float4*)((ch ? po : td) + gr*W_ + (c4*4 - 4));
        *(float4*)&inL[(ch*ST_ROWS + row)*LSTR + c4*4] = v;
    }
    __syncthreads();

    const float a = sa[0];
    const int rowblk = 2 - g/12;
    const int colblk = g % 12;
    float* cbase = ws + WS_CANVAS + (size_t)b*CANVAS_PX
                 + (size_t)(rowblk*H_ + r0)*CANVAS_W + colblk*W_;
    for (int t = tid; t < OUT_H*40; t += 256) {
        const int yr = t / 40;
        const int s  = t % 40;
        const int x0 = s*4;
        float4 acc = z4;
        #pragma unroll 1
        for (int ky = 0; ky < 5; ++ky) {
            const float* p0 = &inL[(yr + ky)*LSTR + x0];
            const float* p1 = &inL[(ST_ROWS + yr + ky)*LSTR + x0];
            float4 A0 = *(const float4*)(p0);
            float4 B0 = *(const float4*)(p0 + 4);
            float4 C0 = *(const float4*)(p0 + 8);
            float4 A1 = *(const float4*)(p1);
            float4 B1 = *(const float4*)(p1 + 4);
            float4 C1 = *(const float4*)(p1 + 8);
            const int k5 = ky*5;
            float u0 = swk[k5], u1 = swk[k5+1], u2 = swk[k5+2], u3 = swk[k5+3], u4 = swk[k5+4];
            ROW_MACN(acc, u0, u1, u2, u3, u4, A0, B0, C0)
            float q0 = swk[25+k5], q1 = swk[26+k5], q2 = swk[27+k5], q3 = swk[28+k5], q4 = swk[29+k5];
            ROW_MACN(acc, q0, q1, q2, q3, q4, A1, B1, C1)
        }
        *(float4*)(cbase + (size_t)yr*CANVAS_W + x0) =
            make_float4(a*acc.x, a*acc.y, a*acc.z, a*acc.w);
    }
}

// ---------------------------------------------------------------------------
// Kernel 3: conv2_1 (k5, stride (5,7), dil 10) + avgpool3x3/3 -> pool1 (ws).
// grid 608, 256 threads.
// ---------------------------------------------------------------------------
__global__ __launch_bounds__(256)
void k_conv2a(const float* __restrict__ w21p, const float* __restrict__ b21p,
              float* __restrict__ ws)
{
    const int blk = blockIdx.x;          // (b*2+ver)*19 + a
    const int a = blk % 19;
    const int bv = blk / 19;
    const int ver = bv & 1;
    const int b = bv >> 1;
    const int coloff = ver ? (CANVAS_W - W_) : 0;   // 1760

    __shared__ float s1[3*267];
    __shared__ float swt[25];
    if (threadIdx.x < 25) swt[threadIdx.x] = w21p[threadIdx.x];
    __syncthreads();
    const float b21 = b21p[0];
    const float* cv = ws + WS_CANVAS + (size_t)b*CANVAS_PX;

    for (int px = threadIdx.x; px < 3*267; px += 256) {
        const int row = px / 267;
        const int v = px % 267;
        const int u = 3*a + row;
        float acc = b21;
        #pragma unroll
        for (int ky = 0; ky < 5; ++ky) {
            const float* rp = cv + (5*u + 10*ky)*CANVAS_W;
            #pragma unroll
            for (int kx = 0; kx < 5; ++kx) {
                int c = 7*v + 10*kx + coloff;
                if (c >= CANVAS_W) c -= CANVAS_W;
                acc += swt[ky*5+kx] * rp[c];
            }
        }
        s1[px] = acc;
    }
    __syncthreads();
    if (threadIdx.x < 89) {
        const int bb = threadIdx.x;
        float s = 0.f;
        #pragma unroll
        for (int i = 0; i < 3; ++i)
            #pragma unroll
            for (int j = 0; j < 3; ++j)
                s += s1[i*267 + 3*bb + j];
        ws[WS_POOL1 + blk*89 + bb] = s * (1.f/9.f);
    }
}

// ---------------------------------------------------------------------------
// Kernel 4: conv2_2 + avgpool(3,9)/3 + v2 roll + combine + flip + softmax/10
// + mask.  grid 16, 256 threads.
// ---------------------------------------------------------------------------
__global__ __launch_bounds__(256)
void k_conv2b(const float* __restrict__ w22p, const float* __restrict__ b22p,
              const int* __restrict__ navidx, float* __restrict__ ws,
              float* __restrict__ out)
{
    const int b = blockIdx.x;
    __shared__ float p[2*19*89];
    __shared__ float s2[2*9*43];
    __shared__ float svf[36];
    __shared__ float sms[2];
    __shared__ float swt[9];

    for (int i = threadIdx.x; i < 2*19*89; i += 256)
        p[i] = ws[WS_POOL1 + (b*2)*19*89 + i];
    if (threadIdx.x < 9) swt[threadIdx.x] = w22p[threadIdx.x];
    const float b22 = b22p[0];
    __syncthreads();

    for (int t = threadIdx.x; t < 2*9*43; t += 256) {
        const int ver = t / 387;
        const int r = t % 387;
        const int pp = r / 43;
        const int q = r % 43;
        float acc = b22;
        #pragma unroll
        for (int i = 0; i < 3; ++i)
            #pragma unroll
            for (int j = 0; j < 3; ++j)
                acc += swt[i*3+j] * p[(ver*19 + (2*pp+i))*89 + 2*q + 2*j];
        s2[ver*387 + pp*43 + q] = acc;
    }
    __syncthreads();

    if (threadIdx.x < 36) {
        const int gg = threadIdx.x;
        const int io = 2 - gg/12;
        const int j  = gg % 12;
        const int j2 = (j + 1) % 12;
        float s = 0.f;
        #pragma unroll
        for (int ii = 0; ii < 3; ++ii)
            #pragma unroll
            for (int jj = 0; jj < 9; ++jj)
                s += s2[(3*io+ii)*43 + 3*j + jj] + s2[387 + (3*io+ii)*43 + 3*j2 + jj];
        svf[gg] = s * (0.5f/27.f);
    }
    __syncthreads();
    if (threadIdx.x == 0) {
        float m = svf[0];
        for (int i = 1; i < 36; ++i) m = fmaxf(m, svf[i]);
        float s = 0.f;
        for (int i = 0; i < 36; ++i) s += expf((svf[i]-m)*0.1f);
        sms[0] = m; sms[1] = s;
    }
    __syncthreads();
    if (threadIdx.x < 36) {
        const float v = expf((svf[threadIdx.x]-sms[0])*0.1f) / sms[1];
        ws[WS_VF + b*36 + threadIdx.x] = v;
        out[16384 + b*36 + threadIdx.x] = v;
    }
    if (threadIdx.x < 37) {
        const int j = threadIdx.x;
        float v = (j == 0) ? 1.f : 0.f;
        #pragma unroll
        for (int t = 0; t < 8; ++t)
            if (navidx[b*8+t] + 1 == j) v = 1.f;
        out[16960 + b*37 + j] = v;
    }
}

// ---------------------------------------------------------------------------
// Kernel 5: LSTM GEMM + pointwise.  grid 256, 256 threads.
// ---------------------------------------------------------------------------
#define CT_STRIDE 20
__global__ __launch_bounds__(256)
void k_lstm(const float* __restrict__ wctx, const float* __restrict__ pre_action,
            const float* __restrict__ h0, const float* __restrict__ c0,
            const float* __restrict__ w_ih, const float* __restrict__ w_hh,
            const float* __restrict__ b_ih, const float* __restrict__ b_hh,
            const float* __restrict__ ws, float* __restrict__ out)
{
    __shared__ float cT[1096*CT_STRIDE];
    __shared__ float red[8*32*16];
    __shared__ float gatev[8][16];
    const int tid = threadIdx.x;

    for (int idx = tid; idx < 1096*16; idx += 256) {
        const int k = idx >> 4;
        const int bb = idx & 15;
        float v;
        if (k < 512)       v = wctx[bb*512 + k];
        else if (k < 548)  v = ws[WS_VF + bb*36 + (k-512)];
        else if (k < 552)  v = ws[WS_FATT + bb*4 + (k-548)];
        else if (k < 584)  v = pre_action[bb*32 + (k-552)];
        else               v = h0[bb*512 + (k-584)];
        cT[k*CT_STRIDE + bb] = v;
    }
    __syncthreads();

    const int rl = tid >> 5;
    const int lane = tid & 31;
    const int u0 = blockIdx.x*2;
    const int ul = rl & 1;
    const int gate = rl >> 1;
    const int r = u0 + ul + gate*512;

    float acc[16];
    #pragma unroll
    for (int i = 0; i < 16; ++i) acc[i] = 0.f;

    const float* wih_r = w_ih + (size_t)r*584;
    for (int k = lane; k < 584; k += 32) {
        const float wv = wih_r[k];
        const float* cp = cT + k*CT_STRIDE;
        #pragma unroll
        for (int i = 0; i < 16; ++i) acc[i] += wv*cp[i];
    }
    const float* whh_r = w_hh + (size_t)r*512;
    for (int k = lane; k < 512; k += 32) {
        const float wv = whh_r[k];
        const float* cp = cT + (584+k)*CT_STRIDE;
        #pragma unroll
        for (int i = 0; i < 16; ++i) acc[i] += wv*cp[i];
    }
    float* rp = red + (rl*32 + lane)*16;
    #pragma unroll
    for (int i = 0; i < 16; ++i) rp[i] = acc[i];
    __syncthreads();

    if (tid < 128) {
        const int rr = tid >> 4;
        const int bb = tid & 15;
        const int rrow = u0 + (rr & 1) + (rr >> 1)*512;
        float s = b_ih[rrow] + b_hh[rrow];
        for (int l = 0; l < 32; ++l) s += red[(rr*32 + l)*16 + bb];
        gatev[rr][bb] = s;
    }
    __syncthreads();

    if (tid < 32) {
        const int ul2 = tid >> 4;
        const int bb = tid & 15;
        const int u = u0 + ul2;
        const float gi = gatev[0+ul2][bb];
        const float gf = gatev[2+ul2][bb];
        const float gg = gatev[4+ul2][bb];
        const float go = gatev[6+ul2][bb];
        const float c1 = sigmoidf_(gf)*c0[bb*512+u] + sigmoidf_(gi)*tanhf(gg);
        const float h1 = sigmoidf_(go)*tanhf(c1);
        out[bb*512 + u] = h1;
        out[8192 + bb*512 + u] = c1;
    }
}

// ---------------------------------------------------------------------------
extern "C" void kernel_launch(void* const* d_in, const int* in_sizes, int n_in,
                              void* d_out, int out_size, void* d_ws, size_t ws_size,
                              hipStream_t stream)
{
    const float* d0        = (const float*)d_in[0];
    const float* d1        = (const float*)d_in[1];
    const float* obj       = (const float*)d_in[2];
    const float* numnav    = (const float*)d_in[3];
    const float* preact    = (const float*)d_in[4];
    const float* h0        = (const float*)d_in[5];
    const float* c0        = (const float*)d_in[6];
    const float* wctx      = (const float*)d_in[7];
    const int*   navidx    = (const int*)d_in[8];
    const float* conv1_w   = (const float*)d_in[9];
    const float* conv1_b   = (const float*)d_in[10];
    const float* dynf      = (const float*)d_in[11];
    const float* dw1       = (const float*)d_in[12];
    const float* db1       = (const float*)d_in[13];
    const float* dw2       = (const float*)d_in[14];
    const float* db2       = (const float*)d_in[15];
    const float* w21       = (const float*)d_in[16];
    const float* b21       = (const float*)d_in[17];
    const float* w22       = (const float*)d_in[18];
    const float* b22       = (const float*)d_in[19];
    const float* wih       = (const float*)d_in[20];
    const float* whh       = (const float*)d_in[21];
    const float* bih       = (const float*)d_in[22];
    const float* bhh       = (const float*)d_in[23];
    float* ws  = (float*)d_ws;
    float* out = (float*)d_out;

    dim3 blk(256);
    k_pre   <<<dim3(16),      blk, 0, stream>>>(wctx, dw1, db1, dw2, db2, dynf, numnav, ws);
    k_td    <<<dim3(10, 576), blk, 0, stream>>>(d0, d1, conv1_w, conv1_b, ws);
    k_dyn   <<<dim3(10, 576), blk, 0, stream>>>(obj, ws);
    k_conv2a<<<dim3(608),     blk, 0, stream>>>(w21, b21, ws);
    k_conv2b<<<dim3(16),      blk, 0, stream>>>(w22, b22, navidx, ws, out);
    k_lstm  <<<dim3(256),     blk, 0, stream>>>(wctx, preact, h0, c0, wih, whh,
                                                bih, bhh, ws, out);
}

// Round 10
// 145.952 us; speedup vs baseline: 3.3269x; 1.4838x over previous
//
#include <hip/hip_runtime.h>
#include <math.h>

#define B_ 16
#define NAV_ 36
#define H_ 120
#define W_ 160
#define HID_ 512
#define PLANES (B_*NAV_)          // 576
#define PLANE_PX (H_*W_)          // 19200
#define CANVAS_H 360
#define CANVAS_W 1920
#define CANVAS_PX (CANVAS_H*CANVAS_W)  // 691200

// f16 LDS-staged conv tiling: band of 12 output rows, 16 staged rows.
// Row stored as 44 8-byte slots; slot j holds elements 4j-2..4j+1 as f16
// (2-element left pad baked in).  ROWB bytes per row.
#define OUT_H 12
#define ST_ROWS 16
#define ROWB 352                  // 44 slots * 8 B
#define CHSTR (ST_ROWS*ROWB)      // 5632 B per channel

// workspace offsets (in floats)
#define WS_NAV    0
#define WS_FATT   576
#define WS_KERN   640
#define WS_TD     29440
#define WS_CANVAS (WS_TD + PLANES*PLANE_PX)
#define WS_POOL1  (WS_CANVAS + B_*CANVAS_PX)
#define WS_VF     (WS_POOL1 + B_*2*19*89)

typedef unsigned int u32;
typedef _Float16 h2_t __attribute__((ext_vector_type(2)));
typedef float float4a __attribute__((ext_vector_type(4), aligned(4)));

__device__ __forceinline__ float sigmoidf_(float x) { return 1.f / (1.f + expf(-x)); }

__device__ __forceinline__ u32 pkh(float a, float b) {
    return __builtin_bit_cast(u32, __builtin_amdgcn_cvt_pkrtz(a, b));
}
__device__ __forceinline__ float dot2h(u32 a, u32 b, float c) {
#if __has_builtin(__builtin_amdgcn_fdot2)
    return __builtin_amdgcn_fdot2(__builtin_bit_cast(h2_t, a),
                                  __builtin_bit_cast(h2_t, b), c, false);
#else
    float r;
    asm("v_dot2_f32_f16 %0, %1, %2, %3" : "=v"(r) : "v"(a), "v"(b), "v"(c));
    return r;
#endif
}

// Stage 2 channels of a 16-row band into f16 slot layout (each byte once).
__device__ __forceinline__ void stage2(unsigned char* lds, const float* s0,
                                       const float* s1, int r0, int tid)
{
    for (int i = tid; i < 2*ST_ROWS*44; i += 256) {
        const int ch  = i / (ST_ROWS*44);
        const int rem = i % (ST_ROWS*44);
        const int rr  = rem / 44;
        const int j   = rem % 44;
        const int gr  = r0 - 2 + rr;
        u32 lo = 0, hi = 0;
        if ((unsigned)gr < (unsigned)H_ && j <= 40) {
            const float* src = (ch ? s1 : s0) + gr*W_;
            if (j == 0) {
                hi = pkh(src[0], src[1]);
            } else if (j < 40) {
                const float4a v = *(const float4a*)(src + 4*j - 2);
                lo = pkh(v.x, v.y);  hi = pkh(v.z, v.w);
            } else {
                lo = pkh(src[158], src[159]);
            }
        }
        *(int2*)(lds + (size_t)ch*CHSTR + rr*ROWB + j*8) = make_int2((int)lo, (int)hi);
    }
}

// 8-px, 2-channel, 5x5 conv via dot2: even px use pairs (w0,w1)(w2,w3)(w4,0),
// odd px use (0,w0)(w1,w2)(w3,w4) against the SAME aligned input pairs.
__device__ __forceinline__ void conv8(const unsigned char* b0, const unsigned char* b1,
                                      const u32* ew, float* acc)
{
    #pragma unroll
    for (int ky = 0; ky < 5; ++ky) {
        const int off = ky*ROWB;
        int4 qa = *(const int4*)(b0 + off);
        int2 qb = *(const int2*)(b0 + off + 16);
        int4 ra = *(const int4*)(b1 + off);
        int2 rb = *(const int2*)(b1 + off + 16);
        u32 P[6] = {(u32)qa.x,(u32)qa.y,(u32)qa.z,(u32)qa.w,(u32)qb.x,(u32)qb.y};
        u32 Q[6] = {(u32)ra.x,(u32)ra.y,(u32)ra.z,(u32)ra.w,(u32)rb.x,(u32)rb.y};
        const u32 e0 = ew[ky*3+0], e1 = ew[ky*3+1], e2 = ew[ky*3+2];
        const u32 f0 = ew[15+ky*3+0], f1 = ew[15+ky*3+1], f2 = ew[15+ky*3+2];
        const u32 o0 = e0 << 16;
        const u32 o1 = __builtin_amdgcn_alignbit(e1, e0, 16);
        const u32 o2 = __builtin_amdgcn_alignbit(e2, e1, 16);
        const u32 g0 = f0 << 16;
        const u32 g1 = __builtin_amdgcn_alignbit(f1, f0, 16);
        const u32 g2 = __builtin_amdgcn_alignbit(f2, f1, 16);
        #pragma unroll
        for (int m = 0; m < 4; ++m) {
            acc[2*m]   = dot2h(e0, P[m], dot2h(e1, P[m+1], dot2h(e2, P[m+2], acc[2*m])));
            acc[2*m+1] = dot2h(o0, P[m], dot2h(o1, P[m+1], dot2h(o2, P[m+2], acc[2*m+1])));
            acc[2*m]   = dot2h(f0, Q[m], dot2h(f1, Q[m+1], dot2h(f2, Q[m+2], acc[2*m])));
            acc[2*m+1] = dot2h(g0, Q[m], dot2h(g1, Q[m+1], dot2h(g2, Q[m+2], acc[2*m+1])));
        }
    }
}

#define LOAD_EW(EW, SW)                                                        \
    {                                                                          \
        _Pragma("unroll")                                                      \
        for (int q = 0; q < 7; ++q) {                                          \
            int4 t = ((const int4*)(SW))[q];                                   \
            EW[4*q]=(u32)t.x; EW[4*q+1]=(u32)t.y; EW[4*q+2]=(u32)t.z; EW[4*q+3]=(u32)t.w; \
        }                                                                      \
        int2 t = ((const int2*)(SW))[14];                                      \
        EW[28]=(u32)t.x; EW[29]=(u32)t.y;                                      \
    }

// ---------------------------------------------------------------------------
// Kernel 1: grouped conv1 -> total_depth (f32 in ws).  grid (11, 576).
// band 10 = folded precompute (filt_attn MLP, dyn kernels, nav softmax).
// ---------------------------------------------------------------------------
__global__ __launch_bounds__(256)
void k_td(const float* __restrict__ d0, const float* __restrict__ d1,
          const float* __restrict__ conv1_w, const float* __restrict__ conv1_b,
          const float* __restrict__ wctx, const float* __restrict__ dw1,
          const float* __restrict__ db1, const float* __restrict__ dw2,
          const float* __restrict__ db2, const float* __restrict__ dynf,
          const float* __restrict__ numnav, float* __restrict__ ws)
{
    const int tid = threadIdx.x;
    const int plane = blockIdx.y;

    __shared__ __align__(16) unsigned char smem[2*CHSTR + 160];
    u32* swt2 = (u32*)(smem + 2*CHSTR);
    float* sextra = (float*)(swt2 + 32);

    if (blockIdx.x == 10) {
        // ---- precompute (one active block per batch) ----
        if (plane % NAV_) return;
        const int b = plane / NAV_;
        float* sh   = (float*)smem;        // 128
        float* sred = sh + 128;            // 8
        float* nv   = sh + 136;            // 36
        float* nms  = sh + 172;            // 2
        if (tid < 128) {
            float acc = db1[tid];
            for (int k = 0; k < HID_; ++k) acc += wctx[b*HID_ + k] * dw1[k*128 + tid];
            sh[tid] = fmaxf(acc, 0.f);
        }
        __syncthreads();
        if (tid < 4) {
            float acc = db2[tid];
            for (int j = 0; j < 128; ++j) acc += sh[j] * dw2[j*4 + tid];
            sred[tid] = acc;
        }
        __syncthreads();
        if (tid == 0) {
            float m = fmaxf(fmaxf(sred[0], sred[1]), fmaxf(sred[2], sred[3]));
            float e0 = expf(sred[0]-m), e1 = expf(sred[1]-m), e2 = expf(sred[2]-m), e3 = expf(sred[3]-m);
            float s = e0+e1+e2+e3;
            sred[4] = e0/s; sred[5] = e1/s; sred[6] = e2/s; sred[7] = e3/s;
            ws[WS_FATT + b*4+0] = sred[4]; ws[WS_FATT + b*4+1] = sred[5];
            ws[WS_FATT + b*4+2] = sred[6]; ws[WS_FATT + b*4+3] = sred[7];
        }
        __syncthreads();
        {
            const float fa0 = sred[4], fa1 = sred[5], fa2 = sred[6], fa3 = sred[7];
            for (int e = tid; e < 1800; e += 256) {
                float v = fa0*dynf[e] + fa1*dynf[1800+e] + fa2*dynf[3600+e] + fa3*dynf[5400+e];
                ws[WS_KERN + b*1800 + e] = v;
            }
        }
        if (tid < 36) nv[tid] = numnav[b*NAV_ + tid];
        __syncthreads();
        if (tid == 0) {
            float m = nv[0];
            for (int i = 1; i < 36; ++i) m = fmaxf(m, nv[i]);
            float s = 0.f;
            for (int i = 0; i < 36; ++i) s += expf(nv[i]-m);
            nms[0] = m; nms[1] = s;
        }
        __syncthreads();
        if (tid < 36) ws[WS_NAV + b*NAV_ + tid] = expf(nv[tid]-nms[0]) / nms[1];
        return;
    }

    // ---- conv path ----
    const int g = plane % NAV_;
    const int r0 = blockIdx.x * OUT_H;

    if (tid < 30) {
        const int ch = tid / 15, ky = (tid % 15) / 3, k = tid % 3;
        const float* wsrc = conv1_w + g*50 + ch*25 + ky*5;
        const float a0 = wsrc[2*k];
        const float a1 = (k < 2) ? wsrc[2*k+1] : 0.f;
        swt2[tid] = pkh(a0, a1);
    }
    if (tid == 30) sextra[0] = conv1_b[g];

    stage2(smem, d0 + (size_t)plane*PLANE_PX, d1 + (size_t)plane*PLANE_PX, r0, tid);
    __syncthreads();

    if (tid < 240) {
        const int yr = tid / 20, s = tid % 20;
        const unsigned char* b0 = smem + yr*ROWB + s*16;
        const unsigned char* b1 = b0 + CHSTR;
        float acc[8];
        #pragma unroll
        for (int p = 0; p < 8; ++p) acc[p] = 0.f;
        u32 ew[30];
        LOAD_EW(ew, swt2)
        conv8(b0, b1, ew, acc);
        const float bias = sextra[0];
        float* outp = ws + WS_TD + (size_t)plane*PLANE_PX + (r0+yr)*W_ + s*8;
        *(float4*)outp     = make_float4(acc[0]+bias, acc[1]+bias, acc[2]+bias, acc[3]+bias);
        *(float4*)(outp+4) = make_float4(acc[4]+bias, acc[5]+bias, acc[6]+bias, acc[7]+bias);
    }
}

// ---------------------------------------------------------------------------
// Kernel 2: dynamic grouped conv (td, obj) -> canvas.  grid (10, 576).
// ---------------------------------------------------------------------------
__global__ __launch_bounds__(256)
void k_dyn(const float* __restrict__ obj, float* __restrict__ ws)
{
    const int tid = threadIdx.x;
    const int plane = blockIdx.y;
    const int b = plane / NAV_;
    const int g = plane % NAV_;
    const int r0 = blockIdx.x * OUT_H;

    __shared__ __align__(16) unsigned char smem[2*CHSTR + 160];
    u32* swt2 = (u32*)(smem + 2*CHSTR);
    float* sextra = (float*)(swt2 + 32);

    if (tid < 30) {
        const int ch = tid / 15, ky = (tid % 15) / 3, k = tid % 3;
        const float* wsrc = ws + WS_KERN + plane*50 + ch*25 + ky*5;
        const float a0 = wsrc[2*k];
        const float a1 = (k < 2) ? wsrc[2*k+1] : 0.f;
        swt2[tid] = pkh(a0, a1);
    }
    if (tid == 30) sextra[0] = ws[WS_NAV + plane];

    stage2(smem, ws + WS_TD + (size_t)plane*PLANE_PX,
           obj + (size_t)plane*PLANE_PX, r0, tid);
    __syncthreads();

    if (tid < 240) {
        const int yr = tid / 20, s = tid % 20;
        const unsigned char* b0 = smem + yr*ROWB + s*16;
        const unsigned char* b1 = b0 + CHSTR;
        float acc[8];
        #pragma unroll
        for (int p = 0; p < 8; ++p) acc[p] = 0.f;
        u32 ew[30];
        LOAD_EW(ew, swt2)
        conv8(b0, b1, ew, acc);
        const float a = sextra[0];
        const int rowblk = 2 - g/12;
        const int colblk = g % 12;
        float* cbase = ws + WS_CANVAS + (size_t)b*CANVAS_PX
                     + (size_t)(rowblk*H_ + r0 + yr)*CANVAS_W + colblk*W_ + s*8;
        *(float4*)cbase     = make_float4(a*acc[0], a*acc[1], a*acc[2], a*acc[3]);
        *(float4*)(cbase+4) = make_float4(a*acc[4], a*acc[5], a*acc[6], a*acc[7]);
    }
}

// ---------------------------------------------------------------------------
// Kernel 3: conv2_1 (k5, stride (5,7), dil 10) + avgpool3x3/3 -> pool1 (ws).
// grid 608, 256 threads.
// ---------------------------------------------------------------------------
__global__ __launch_bounds__(256)
void k_conv2a(const float* __restrict__ w21p, const float* __restrict__ b21p,
              float* __restrict__ ws)
{
    const int blk = blockIdx.x;          // (b*2+ver)*19 + a
    const int a = blk % 19;
    const int bv = blk / 19;
    const int ver = bv & 1;
    const int b = bv >> 1;
    const int coloff = ver ? (CANVAS_W - W_) : 0;   // 1760

    __shared__ float s1[3*267];
    __shared__ float swt[25];
    if (threadIdx.x < 25) swt[threadIdx.x] = w21p[threadIdx.x];
    __syncthreads();
    const float b21 = b21p[0];
    const float* cv = ws + WS_CANVAS + (size_t)b*CANVAS_PX;

    for (int px = threadIdx.x; px < 3*267; px += 256) {
        const int row = px / 267;
        const int v = px % 267;
        const int u = 3*a + row;
        float acc = b21;
        #pragma unroll
        for (int ky = 0; ky < 5; ++ky) {
            const float* rp = cv + (5*u + 10*ky)*CANVAS_W;
            #pragma unroll
            for (int kx = 0; kx < 5; ++kx) {
                int c = 7*v + 10*kx + coloff;
                if (c >= CANVAS_W) c -= CANVAS_W;
                acc += swt[ky*5+kx] * rp[c];
            }
        }
        s1[px] = acc;
    }
    __syncthreads();
    if (threadIdx.x < 89) {
        const int bb = threadIdx.x;
        float s = 0.f;
        #pragma unroll
        for (int i = 0; i < 3; ++i)
            #pragma unroll
            for (int j = 0; j < 3; ++j)
                s += s1[i*267 + 3*bb + j];
        ws[WS_POOL1 + blk*89 + bb] = s * (1.f/9.f);
    }
}

// ---------------------------------------------------------------------------
// Kernel 4: conv2_2 + avgpool(3,9)/3 + v2 roll + combine + flip + softmax/10
// + mask.  grid 16, 256 threads.
// ---------------------------------------------------------------------------
__global__ __launch_bounds__(256)
void k_conv2b(const float* __restrict__ w22p, const float* __restrict__ b22p,
              const int* __restrict__ navidx, float* __restrict__ ws,
              float* __restrict__ out)
{
    const int b = blockIdx.x;
    __shared__ float p[2*19*89];
    __shared__ float s2[2*9*43];
    __shared__ float svf[36];
    __shared__ float sms[2];
    __shared__ float swt[9];

    for (int i = threadIdx.x; i < 2*19*89; i += 256)
        p[i] = ws[WS_POOL1 + (b*2)*19*89 + i];
    if (threadIdx.x < 9) swt[threadIdx.x] = w22p[threadIdx.x];
    const float b22 = b22p[0];
    __syncthreads();

    for (int t = threadIdx.x; t < 2*9*43; t += 256) {
        const int ver = t / 387;
        const int r = t % 387;
        const int pp = r / 43;
        const int q = r % 43;
        float acc = b22;
        #pragma unroll
        for (int i = 0; i < 3; ++i)
            #pragma unroll
            for (int j = 0; j < 3; ++j)
                acc += swt[i*3+j] * p[(ver*19 + (2*pp+i))*89 + 2*q + 2*j];
        s2[ver*387 + pp*43 + q] = acc;
    }
    __syncthreads();

    if (threadIdx.x < 36) {
        const int gg = threadIdx.x;
        const int io = 2 - gg/12;
        const int j  = gg % 12;
        const int j2 = (j + 1) % 12;
        float s = 0.f;
        #pragma unroll
        for (int ii = 0; ii < 3; ++ii)
            #pragma unroll
            for (int jj = 0; jj < 9; ++jj)
                s += s2[(3*io+ii)*43 + 3*j + jj] + s2[387 + (3*io+ii)*43 + 3*j2 + jj];
        svf[gg] = s * (0.5f/27.f);
    }
    __syncthreads();
    if (threadIdx.x == 0) {
        float m = svf[0];
        for (int i = 1; i < 36; ++i) m = fmaxf(m, svf[i]);
        float s = 0.f;
        for (int i = 0; i < 36; ++i) s += expf((svf[i]-m)*0.1f);
        sms[0] = m; sms[1] = s;
    }
    __syncthreads();
    if (threadIdx.x < 36) {
        const float v = expf((svf[threadIdx.x]-sms[0])*0.1f) / sms[1];
        ws[WS_VF + b*36 + threadIdx.x] = v;
        out[16384 + b*36 + threadIdx.x] = v;
    }
    if (threadIdx.x < 37) {
        const int j = threadIdx.x;
        float v = (j == 0) ? 1.f : 0.f;
        #pragma unroll
        for (int t = 0; t < 8; ++t)
            if (navidx[b*8+t] + 1 == j) v = 1.f;
        out[16960 + b*37 + j] = v;
    }
}

// ---------------------------------------------------------------------------
// Kernel 5: LSTM GEMM + pointwise.  grid 256, 256 threads.
// ---------------------------------------------------------------------------
#define CT_STRIDE 20
__global__ __launch_bounds__(256)
void k_lstm(const float* __restrict__ wctx, const float* __restrict__ pre_action,
            const float* __restrict__ h0, const float* __restrict__ c0,
            const float* __restrict__ w_ih, const float* __restrict__ w_hh,
            const float* __restrict__ b_ih, const float* __restrict__ b_hh,
            const float* __restrict__ ws, float* __restrict__ out)
{
    __shared__ float cT[1096*CT_STRIDE];
    __shared__ float red[8*32*16];
    __shared__ float gatev[8][16];
    const int tid = threadIdx.x;

    for (int idx = tid; idx < 1096*16; idx += 256) {
        const int k = idx >> 4;
        const int bb = idx & 15;
        float v;
        if (k < 512)       v = wctx[bb*512 + k];
        else if (k < 548)  v = ws[WS_VF + bb*36 + (k-512)];
        else if (k < 552)  v = ws[WS_FATT + bb*4 + (k-548)];
        else if (k < 584)  v = pre_action[bb*32 + (k-552)];
        else               v = h0[bb*512 + (k-584)];
        cT[k*CT_STRIDE + bb] = v;
    }
    __syncthreads();

    const int rl = tid >> 5;
    const int lane = tid & 31;
    const int u0 = blockIdx.x*2;
    const int ul = rl & 1;
    const int gate = rl >> 1;
    const int r = u0 + ul + gate*512;

    float acc[16];
    #pragma unroll
    for (int i = 0; i < 16; ++i) acc[i] = 0.f;

    const float* wih_r = w_ih + (size_t)r*584;
    for (int k = lane; k < 584; k += 32) {
        const float wv = wih_r[k];
        const float* cp = cT + k*CT_STRIDE;
        #pragma unroll
        for (int i = 0; i < 16; ++i) acc[i] += wv*cp[i];
    }
    const float* whh_r = w_hh + (size_t)r*512;
    for (int k = lane; k < 512; k += 32) {
        const float wv = whh_r[k];
        const float* cp = cT + (584+k)*CT_STRIDE;
        #pragma unroll
        for (int i = 0; i < 16; ++i) acc[i] += wv*cp[i];
    }
    float* rp = red + (rl*32 + lane)*16;
    #pragma unroll
    for (int i = 0; i < 16; ++i) rp[i] = acc[i];
    __syncthreads();

    if (tid < 128) {
        const int rr = tid >> 4;
        const int bb = tid & 15;
        const int rrow = u0 + (rr & 1) + (rr >> 1)*512;
        float s = b_ih[rrow] + b_hh[rrow];
        for (int l = 0; l < 32; ++l) s += red[(rr*32 + l)*16 + bb];
        gatev[rr][bb] = s;
    }
    __syncthreads();

    if (tid < 32) {
        const int ul2 = tid >> 4;
        const int bb = tid & 15;
        const int u = u0 + ul2;
        const float gi = gatev[0+ul2][bb];
        const float gf = gatev[2+ul2][bb];
        const float gg = gatev[4+ul2][bb];
        const float go = gatev[6+ul2][bb];
        const float c1 = sigmoidf_(gf)*c0[bb*512+u] + sigmoidf_(gi)*tanhf(gg);
        const float h1 = sigmoidf_(go)*tanhf(c1);
        out[bb*512 + u] = h1;
        out[8192 + bb*512 + u] = c1;
    }
}

// ---------------------------------------------------------------------------
extern "C" void kernel_launch(void* const* d_in, const int* in_sizes, int n_in,
                              void* d_out, int out_size, void* d_ws, size_t ws_size,
                              hipStream_t stream)
{
    const float* d0        = (const float*)d_in[0];
    const float* d1        = (const float*)d_in[1];
    const float* obj       = (const float*)d_in[2];
    const float* numnav    = (const float*)d_in[3];
    const float* preact    = (const float*)d_in[4];
    const float* h0        = (const float*)d_in[5];
    const float* c0        = (const float*)d_in[6];
    const float* wctx      = (const float*)d_in[7];
    const int*   navidx    = (const int*)d_in[8];
    const float* conv1_w   = (const float*)d_in[9];
    const float* conv1_b   = (const float*)d_in[10];
    const float* dynf      = (const float*)d_in[11];
    const float* dw1       = (const float*)d_in[12];
    const float* db1       = (const float*)d_in[13];
    const float* dw2       = (const float*)d_in[14];
    const float* db2       = (const float*)d_in[15];
    const float* w21       = (const float*)d_in[16];
    const float* b21       = (const float*)d_in[17];
    const float* w22       = (const float*)d_in[18];
    const float* b22       = (const float*)d_in[19];
    const float* wih       = (const float*)d_in[20];
    const float* whh       = (const float*)d_in[21];
    const float* bih       = (const float*)d_in[22];
    const float* bhh       = (const float*)d_in[23];
    float* ws  = (float*)d_ws;
    float* out = (float*)d_out;

    dim3 blk(256);
    k_td    <<<dim3(11, 576), blk, 0, stream>>>(d0, d1, conv1_w, conv1_b, wctx,
                                                dw1, db1, dw2, db2, dynf, numnav, ws);
    k_dyn   <<<dim3(10, 576), blk, 0, stream>>>(obj, ws);
    k_conv2a<<<dim3(608),     blk, 0, stream>>>(w21, b21, ws);
    k_conv2b<<<dim3(16),      blk, 0, stream>>>(w22, b22, navidx, ws, out);
    k_lstm  <<<dim3(256),     blk, 0, stream>>>(wctx, preact, h0, c0, wih, whh,
                                                bih, bhh, ws, out);
}